// Round 4
// baseline (19721.230 us; speedup 1.0000x reference)
//
#include <hip/hip_runtime.h>
#include <cstdint>

// GRU B=64 T=512 D=1024 H=1024, fp32 in/out, bf16 MFMA internally.
// [x-proj big GEMM -> bf16 Xq with bias] -> [sequential recurrence: 64 wgs x
// 1024 thr, LDS-resident weight slices, 2 FENCE-FREE grid barriers/step
// (flag store + 64-lane poll), cross-wg data via relaxed agent atomics (sc1,
// LLC-coherent), out-projection fused into barrier-wait windows].

typedef float f32x4 __attribute__((ext_vector_type(4)));
typedef short s16x8 __attribute__((ext_vector_type(8)));

#define AS_G const __attribute__((address_space(1))) unsigned int*
#define AS_L __attribute__((address_space(3))) unsigned int*

__device__ __forceinline__ unsigned short f2bf(float f) {
  union { float f; unsigned int u; } v; v.f = f;
  return (unsigned short)((v.u + 0x7FFFu + ((v.u >> 16) & 1u)) >> 16);
}
__device__ __forceinline__ float bf2f(unsigned short s) {
  union { unsigned int u; float f; } v; v.u = ((unsigned int)s) << 16;
  return v.f;
}

// ---- relaxed agent-scope atomics: plain sc1 ops at the coherent point (LLC),
// no cache-wide fences. Used for ALL cross-wg mutable data.
__device__ __forceinline__ void g_store32(unsigned int* p, unsigned int v) {
  __hip_atomic_store(p, v, __ATOMIC_RELAXED, __HIP_MEMORY_SCOPE_AGENT);
}
__device__ __forceinline__ unsigned int g_load32(const unsigned int* p) {
  return __hip_atomic_load((unsigned int*)p, __ATOMIC_RELAXED, __HIP_MEMORY_SCOPE_AGENT);
}
__device__ __forceinline__ void g_storef(float* p, float v) {
  union { float f; unsigned int u; } c; c.f = v;
  g_store32((unsigned int*)p, c.u);
}
__device__ __forceinline__ float g_loadf(const float* p) {
  union { unsigned int u; float f; } c; c.u = g_load32((const unsigned int*)p);
  return c.f;
}
__device__ __forceinline__ s16x8 ld8(const unsigned long long* p) {  // 16B via 2x8B
  unsigned long long a = __hip_atomic_load((unsigned long long*)p, __ATOMIC_RELAXED,
                                           __HIP_MEMORY_SCOPE_AGENT);
  unsigned long long b = __hip_atomic_load((unsigned long long*)p + 1, __ATOMIC_RELAXED,
                                           __HIP_MEMORY_SCOPE_AGENT);
  union { unsigned long long q[2]; s16x8 v; } u;
  u.q[0] = a; u.q[1] = b;
  return u.v;
}

// ---------------- init / guard ----------------
__global__ void init_state(float* __restrict__ h, unsigned int* __restrict__ hbf2,
                           unsigned int* __restrict__ bar) {
  int i = blockIdx.x * 256 + threadIdx.x;  // 65536 threads
  h[i] = 0.f;
  hbf2[i] = 0u;                            // zeroes both packed hbf ping-pong bufs
  if (i < 32768) bar[i] = 0u;
}

__global__ void fill_sentinel(float* o, int n) {
  for (int i = blockIdx.x * 256 + threadIdx.x; i < n; i += gridDim.x * 256)
    o[i] = 1.0e6f;  // recognizable "ws too small" marker
}

// ---------------- weight transpose: fp32 [1024][1024] (row stride 1024) -> bf16 [C][R]
__global__ void transpose_w(const float* __restrict__ src, short* __restrict__ dst) {
  __shared__ float t[32][33];
  const int bx = blockIdx.x, by = blockIdx.y;
  const int c = threadIdx.x & 31, r8 = threadIdx.x >> 5;
#pragma unroll
  for (int j = 0; j < 4; ++j) {
    int r = r8 + j * 8;
    t[r][c] = src[(by * 32 + r) * 1024 + bx * 32 + c];
  }
  __syncthreads();
#pragma unroll
  for (int j = 0; j < 4; ++j) {
    int d = r8 + j * 8;
    dst[(bx * 32 + d) * 1024 + by * 32 + c] = (short)f2bf(t[c][d]);
  }
}

// ---------------- X fp32 -> bf16 (layout-preserving), 8 elems/thread
__global__ void conv_x(const float* __restrict__ x, short* __restrict__ xb) {
  int i = blockIdx.x * 256 + threadIdx.x;  // 4,194,304 threads
  const float4* p = reinterpret_cast<const float4*>(x) + (size_t)i * 2;
  float4 a = p[0], b = p[1];
  s16x8 o;
  o[0] = (short)f2bf(a.x); o[1] = (short)f2bf(a.y);
  o[2] = (short)f2bf(a.z); o[3] = (short)f2bf(a.w);
  o[4] = (short)f2bf(b.x); o[5] = (short)f2bf(b.y);
  o[6] = (short)f2bf(b.z); o[7] = (short)f2bf(b.w);
  *reinterpret_cast<s16x8*>(xb + (size_t)i * 8) = o;
}

// ---------------- x-projection GEMM: [32768,1024]bf16 x [3072,1024]^T bf16
// -> bf16 Xq{r,z,l} in [t][b][h] layout with bias folded (128x128 tile).
__global__ __launch_bounds__(256) void gemm_x(
    const short* __restrict__ A, const short* __restrict__ Bt,
    unsigned short* __restrict__ Xqr, unsigned short* __restrict__ Xqz,
    unsigned short* __restrict__ Xql,
    const float* __restrict__ br, const float* __restrict__ bz,
    const float* __restrict__ bl) {
  __shared__ short As[128 * 64];
  __shared__ short Bs[128 * 64];
  const int tid = threadIdx.x, wv = tid >> 6, l = tid & 63, lr = l & 15, lk = l >> 4;
  // XCD-chunked swizzle (T1): hw id lin -> logical tile swz; 6144 % 8 == 0.
  const int lin = blockIdx.y * 24 + blockIdx.x;
  const int swz = (lin & 7) * 768 + (lin >> 3);
  const int bx = swz % 24, by = swz / 24;
  const int mh = wv >> 1, nh = wv & 1;

  f32x4 acc[4][4];
#pragma unroll
  for (int i = 0; i < 4; ++i)
#pragma unroll
    for (int j = 0; j < 4; ++j) acc[i][j] = (f32x4)0.f;

  const short* Ablk = A + (size_t)by * 128 * 1024;
  const short* Bblk = Bt + (size_t)bx * 128 * 1024;

  for (int kt = 0; kt < 16; ++kt) {
    __syncthreads();
    {
      const short* srcA = Ablk + kt * 64;
      const short* srcB = Bblk + kt * 64;
#pragma unroll
      for (int j = 0; j < 4; ++j) {
        int ubase = j * 256 + wv * 64;  // wave-uniform 16B-unit base
        int u = ubase + l;
        int r = u >> 3, cp = u & 7, c = cp ^ (r & 7);  // source-side pre-swizzle
        __builtin_amdgcn_global_load_lds((AS_G)(srcA + r * 1024 + c * 8),
                                         (AS_L)(As + ubase * 8), 16, 0, 0);
        __builtin_amdgcn_global_load_lds((AS_G)(srcB + r * 1024 + c * 8),
                                         (AS_L)(Bs + ubase * 8), 16, 0, 0);
      }
    }
    __syncthreads();
#pragma unroll
    for (int kc = 0; kc < 2; ++kc) {
      s16x8 af[4], bfr[4];
#pragma unroll
      for (int mt = 0; mt < 4; ++mt) {
        int r = mh * 64 + mt * 16 + lr;
        af[mt] = *(const s16x8*)(As + r * 64 + ((((kc << 2) + lk) ^ (r & 7)) << 3));
      }
#pragma unroll
      for (int nt = 0; nt < 4; ++nt) {
        int r = nh * 64 + nt * 16 + lr;
        bfr[nt] = *(const s16x8*)(Bs + r * 64 + ((((kc << 2) + lk) ^ (r & 7)) << 3));
      }
#pragma unroll
      for (int mt = 0; mt < 4; ++mt)
#pragma unroll
        for (int nt = 0; nt < 4; ++nt)
          acc[mt][nt] = __builtin_amdgcn_mfma_f32_16x16x32_bf16(af[mt], bfr[nt],
                                                                acc[mt][nt], 0, 0, 0);
    }
  }

  // epilogue: each bx block lies fully inside one 1024-col segment (1024/128=8)
  const int seg = bx >> 3;  // 0:r 1:z 2:l
  const float* __restrict__ bias = seg == 0 ? br : (seg == 1 ? bz : bl);
  unsigned short* __restrict__ dst = seg == 0 ? Xqr : (seg == 1 ? Xqz : Xql);
  const int cbase = (bx & 7) * 128 + nh * 64;
#pragma unroll
  for (int mt = 0; mt < 4; ++mt) {
#pragma unroll
    for (int j = 0; j < 4; ++j) {
      int R = by * 128 + mh * 64 + mt * 16 + lk * 4 + j;  // A row = b*512+t
      int tt = R & 511, b = R >> 9;
      size_t drow = ((size_t)((tt << 6) + b)) << 10;      // [t][b] order
#pragma unroll
      for (int nt = 0; nt < 4; ++nt) {
        int c = cbase + nt * 16 + lr;
        dst[drow + c] = f2bf(acc[mt][nt][j] + bias[c]);
      }
    }
  }
}

// ---------------- fence-free grid barrier ----------------
// bar: 64 flags, one per wg, padded to 64 B. Arrival: monotone counter store
// (no RMW). Wait: wave 0's 64 lanes each poll one wg's flag (parallel loads).
__device__ __forceinline__ void bar_arrive(unsigned int* bar, int g, unsigned int val) {
  __syncthreads();  // drains vmcnt: this wg's sc1 stores reached the LLC
  if (threadIdx.x == 0) g_store32(&bar[g << 4], val);
}
__device__ __forceinline__ void bar_wait(unsigned int* bar, unsigned int val,
                                         int wv, int l) {
  if (wv == 0) {
    while (g_load32(&bar[l << 4]) < val) __builtin_amdgcn_s_sleep(4);
  }
  __syncthreads();
}

// ---------------- fused out-projection helpers ----------------
// ldfrag: prefetch Wo (cached) + h (atomic) fragments into registers before
// bar_arrive; MFMA runs inside the wait window.
__device__ __forceinline__ void ldfrag(const short* __restrict__ WoT,
                                       const unsigned long long* __restrict__ hp,
                                       int g, int lr, int lk, int k8, int mo,
                                       int oh, s16x8 wo[4], s16x8 hf[4]) {
#pragma unroll
  for (int kc = 0; kc < 4; ++kc) {
    const int k0 = (k8 << 7) + (kc << 5) + (lk << 3);
    wo[kc] = *(const s16x8*)(WoT + (((size_t)(g << 4) + lr) << 10) + k0);
    hf[kc] = ld8(hp + (((oh * 32 + mo * 16 + lr)) << 8) + (k0 >> 2));
  }
}
// outproj: relu(h_{tOut} @ Wo + bo) for one 32-row half. redf viewed [8][32][18].
__device__ __forceinline__ void outproj(const s16x8 wo[4], const s16x8 hf[4],
                                        const float* __restrict__ bo,
                                        float* __restrict__ out, float* redf,
                                        int g, int tid, int lr, int lk, int k8,
                                        int mo, int tOut, int oh) {
  f32x4 acc = (f32x4)0.f;
#pragma unroll
  for (int kc = 0; kc < 4; ++kc)
    acc = __builtin_amdgcn_mfma_f32_16x16x32_bf16(hf[kc], wo[kc], acc, 0, 0, 0);
  __syncthreads();  // prior red readers done before overwrite
#pragma unroll
  for (int j = 0; j < 4; ++j)
    redf[((k8 << 5) + mo * 16 + lk * 4 + j) * 18 + lr] = acc[j];
  __syncthreads();
  if (tid < 512) {
    const int r = tid >> 4, c = tid & 15;
    float s = 0.f;
#pragma unroll
    for (int q = 0; q < 8; ++q) s += redf[((q << 5) + r) * 18 + c];
    const int gcol = (g << 4) + c;
    const int brow = oh * 32 + r;
    out[(((size_t)brow << 9) + (size_t)tOut) * 1024 + gcol] = fmaxf(s + bo[gcol], 0.f);
  }
}

// ---------------- sequential recurrence: 64 wgs x 1024 threads (16 waves)
// Phase A: [r|z] = sigmoid(h@Wrz_h + Xq_rz), wg owns 32 of 2048 cols.
// Phase B: hh = tanh((h.r)@Wl_h + Xql); h' = (1-z)h + z*hh; wg owns 16 cols.
// Out-proj for step t-1 fused into each barrier-wait window (M-halves).
__global__ __launch_bounds__(1024) void seq_kernel(
    const short* __restrict__ WrzT, const short* __restrict__ WlT,
    const short* __restrict__ WoT,
    const unsigned int* __restrict__ Xqr, const unsigned int* __restrict__ Xqz,
    const unsigned int* __restrict__ Xql, const float* __restrict__ bo,
    float* __restrict__ h, unsigned int* __restrict__ hbf01,
    unsigned int* __restrict__ hrbf, float* __restrict__ zbuf,
    float* __restrict__ out, unsigned int* __restrict__ bar) {
  __shared__ short WrzS[32 * 1024];   // 64 KiB, swizzled 16B units
  __shared__ short WlS[16 * 1024];    // 32 KiB, swizzled
  __shared__ float red[4][64][37];    // 37 KiB cross-wave K-reduction (padded)

  const int g = blockIdx.x, tid = threadIdx.x;
  const int wv = tid >> 6, l = tid & 63, lr = l & 15, lk = l >> 4;
  float* redf = &red[0][0][0];

  // ---- stage weight slices into LDS (XOR-swizzled 16B units) ----
  for (int u = tid; u < 32 * 128; u += 1024) {
    int row = u >> 7, ku = u & 127;
    s16x8 v = *(const s16x8*)(WrzT + (((size_t)(g * 32 + row)) << 10) + (ku << 3));
    *(s16x8*)(WrzS + (row << 10) + ((ku ^ (row & 7)) << 3)) = v;
  }
  for (int u = tid; u < 16 * 128; u += 1024) {
    int row = u >> 7, ku = u & 127;
    s16x8 v = *(const s16x8*)(WlT + (((size_t)(g * 16 + row)) << 10) + (ku << 3));
    *(s16x8*)(WlS + (row << 10) + ((ku ^ (row & 7)) << 3)) = v;
  }
  __syncthreads();

  // wave roles
  const int kqA = wv & 3, nhA = (wv >> 2) & 1, mhA = wv >> 3;  // phase A
  const int browA = nhA * 16 + lr;
  const int kqB = wv & 3, mqB = wv >> 2;                       // phase B
  const int k8 = wv & 7, mo = wv >> 3;                         // out-proj
  const int erow = tid >> 4, ec2 = (tid & 15) << 1;            // phase A epilogue
  const int brow = tid >> 3, bc2 = (tid & 7) << 1;             // phase B epilogue

  for (int t = 0; t < 512; ++t) {
    const unsigned long long* hp =
        (const unsigned long long*)(hbf01 + (((t + 1) & 1) << 15));  // h_{t-1}
    unsigned int* hcur = hbf01 + ((t & 1) << 15);                    // h_t
    // ================= Phase A =================
    {
      f32x4 acc0 = (f32x4)0.f, acc1 = (f32x4)0.f;
#pragma unroll 2
      for (int kc = 0; kc < 8; ++kc) {
        const int k0 = (kqA << 8) + (kc << 5) + (lk << 3);
        const int ku = k0 >> 3;
        s16x8 bb = *(const s16x8*)(WrzS + (browA << 10) + ((ku ^ (browA & 7)) << 3));
        s16x8 a0 = ld8(hp + ((mhA * 32 + lr) << 8) + (k0 >> 2));
        s16x8 a1 = ld8(hp + ((mhA * 32 + 16 + lr) << 8) + (k0 >> 2));
        acc0 = __builtin_amdgcn_mfma_f32_16x16x32_bf16(a0, bb, acc0, 0, 0, 0);
        acc1 = __builtin_amdgcn_mfma_f32_16x16x32_bf16(a1, bb, acc1, 0, 0, 0);
      }
      // epilogue prefetch: adjacent col pair (ec2, ec2+1) of wg's 32-col slice
      float xq0, xq1, hv0 = 0.f, hv1 = 0.f;
      const size_t xrow = (((size_t)t << 6) + erow) << 9;  // uint-pair row base
      if (g < 32) {
        const int gc = (g << 5) + ec2;
        unsigned int xq = Xqr[xrow + (gc >> 1)];
        xq0 = bf2f((unsigned short)xq);
        xq1 = bf2f((unsigned short)(xq >> 16));
        hv0 = g_loadf(&h[(erow << 10) + gc]);
        hv1 = g_loadf(&h[(erow << 10) + gc + 1]);
      } else {
        const int gc = ((g - 32) << 5) + ec2;
        unsigned int xq = Xqz[xrow + (gc >> 1)];
        xq0 = bf2f((unsigned short)xq);
        xq1 = bf2f((unsigned short)(xq >> 16));
      }
#pragma unroll
      for (int j = 0; j < 4; ++j) {
        red[kqA][mhA * 32 + lk * 4 + j][nhA * 16 + lr] = acc0[j];
        red[kqA][mhA * 32 + 16 + lk * 4 + j][nhA * 16 + lr] = acc1[j];
      }
      __syncthreads();
      float s0 = red[0][erow][ec2] + red[1][erow][ec2] + red[2][erow][ec2] +
                 red[3][erow][ec2] + xq0;
      float s1 = red[0][erow][ec2 + 1] + red[1][erow][ec2 + 1] +
                 red[2][erow][ec2 + 1] + red[3][erow][ec2 + 1] + xq1;
      if (g < 32) {
        const int gc = (g << 5) + ec2;
        float r0 = 1.f / (1.f + __expf(-s0));
        float r1 = 1.f / (1.f + __expf(-s1));
        unsigned int pk = (unsigned int)f2bf(hv0 * r0) |
                          ((unsigned int)f2bf(hv1 * r1) << 16);
        g_store32(&hrbf[(erow << 9) + (gc >> 1)], pk);
      } else {
        const int gc = ((g - 32) << 5) + ec2;
        g_storef(&zbuf[(erow << 10) + gc], 1.f / (1.f + __expf(-s0)));
        g_storef(&zbuf[(erow << 10) + gc + 1], 1.f / (1.f + __expf(-s1)));
      }
    }
    s16x8 wo0[4], hf0[4];
    if (t > 0) ldfrag(WoT, hp, g, lr, lk, k8, mo, 0, wo0, hf0);
    bar_arrive(bar, g, 2 * t + 1);
    if (t > 0) outproj(wo0, hf0, bo, out, redf, g, tid, lr, lk, k8, mo, t - 1, 0);
    bar_wait(bar, 2 * t + 1, wv, l);
    // ================= Phase B =================
    {
      const unsigned long long* hrp = (const unsigned long long*)hrbf;
      f32x4 acc = (f32x4)0.f;
#pragma unroll 2
      for (int kc = 0; kc < 8; ++kc) {
        const int k0 = (kqB << 8) + (kc << 5) + (lk << 3);
        const int ku = k0 >> 3;
        s16x8 bb = *(const s16x8*)(WlS + (lr << 10) + ((ku ^ (lr & 7)) << 3));
        s16x8 af = ld8(hrp + ((mqB * 16 + lr) << 8) + (k0 >> 2));
        acc = __builtin_amdgcn_mfma_f32_16x16x32_bf16(af, bb, acc, 0, 0, 0);
      }
#pragma unroll
      for (int j = 0; j < 4; ++j) red[kqB][mqB * 16 + lk * 4 + j][lr] = acc[j];
      __syncthreads();
      if (tid < 512) {  // 64 rows x 8 col-pairs of wg's 16-col slice
        const int gc = (g << 4) + bc2;
        unsigned int xq = Xql[((((size_t)t << 6) + brow) << 9) + (gc >> 1)];
        float x0 = bf2f((unsigned short)xq), x1 = bf2f((unsigned short)(xq >> 16));
        float z0 = g_loadf(&zbuf[(brow << 10) + gc]);
        float z1 = g_loadf(&zbuf[(brow << 10) + gc + 1]);
        float hv0 = g_loadf(&h[(brow << 10) + gc]);
        float hv1 = g_loadf(&h[(brow << 10) + gc + 1]);
        float p0 = red[0][brow][bc2] + red[1][brow][bc2] + red[2][brow][bc2] +
                   red[3][brow][bc2] + x0;
        float p1 = red[0][brow][bc2 + 1] + red[1][brow][bc2 + 1] +
                   red[2][brow][bc2 + 1] + red[3][brow][bc2 + 1] + x1;
        float a0 = fabsf(p0), a1 = fabsf(p1);
        float e0 = __expf(-2.f * a0), e1 = __expf(-2.f * a1);
        float m0 = (1.f - e0) / (1.f + e0), m1 = (1.f - e1) / (1.f + e1);
        float hh0 = p0 < 0.f ? -m0 : m0, hh1 = p1 < 0.f ? -m1 : m1;
        float hn0 = hv0 + z0 * (hh0 - hv0);
        float hn1 = hv1 + z1 * (hh1 - hv1);
        g_storef(&h[(brow << 10) + gc], hn0);
        g_storef(&h[(brow << 10) + gc + 1], hn1);
        unsigned int pk = (unsigned int)f2bf(hn0) | ((unsigned int)f2bf(hn1) << 16);
        g_store32(&hcur[(brow << 9) + (gc >> 1)], pk);
      }
    }
    s16x8 wo1[4], hf1[4];
    if (t > 0) ldfrag(WoT, hp, g, lr, lk, k8, mo, 1, wo1, hf1);
    bar_arrive(bar, g, 2 * t + 2);
    if (t > 0) outproj(wo1, hf1, bo, out, redf, g, tid, lr, lk, k8, mo, t - 1, 1);
    bar_wait(bar, 2 * t + 2, wv, l);
  }
  // final output row block (t = 511): h_511 is in hbf01 buffer 1
  {
    const unsigned long long* hlast =
        (const unsigned long long*)(hbf01 + (1 << 15));
    s16x8 wo[4], hf[4];
    ldfrag(WoT, hlast, g, lr, lk, k8, mo, 0, wo, hf);
    outproj(wo, hf, bo, out, redf, g, tid, lr, lk, k8, mo, 511, 0);
    ldfrag(WoT, hlast, g, lr, lk, k8, mo, 1, wo, hf);
    outproj(wo, hf, bo, out, redf, g, tid, lr, lk, k8, mo, 511, 1);
  }
}

// ---------------- host ----------------
extern "C" void kernel_launch(void* const* d_in, const int* in_sizes, int n_in,
                              void* d_out, int out_size, void* d_ws, size_t ws_size,
                              hipStream_t stream) {
  (void)in_sizes; (void)n_in;
  const float* X  = (const float*)d_in[0];
  const float* Wr = (const float*)d_in[1];
  const float* br = (const float*)d_in[2];
  const float* Wz = (const float*)d_in[3];
  const float* bz = (const float*)d_in[4];
  const float* Wl = (const float*)d_in[5];
  const float* bl = (const float*)d_in[6];
  const float* Wo = (const float*)d_in[7];
  const float* bo = (const float*)d_in[8];
  float* out = (float*)d_out;

  char* ws = (char*)d_ws;
  size_t off = 0;
  auto alloc = [&](size_t bytes) -> char* {
    char* p = ws + off;
    off += (bytes + 255) & ~(size_t)255;
    return p;
  };
  short* WrzT = (short*)alloc((size_t)2048 * 1024 * 2);   // [Wr_h^T ; Wz_h^T]
  short* WlT  = (short*)alloc((size_t)1024 * 1024 * 2);
  short* WoT  = (short*)alloc((size_t)1024 * 1024 * 2);
  short* WxT  = (short*)alloc((size_t)3072 * 1024 * 2);   // [Wr_x^T;Wz_x^T;Wl_x^T]
  short* Xbf  = (short*)alloc((size_t)32768 * 1024 * 2);
  unsigned short* Xqr = (unsigned short*)alloc((size_t)32768 * 1024 * 2);
  unsigned short* Xqz = (unsigned short*)alloc((size_t)32768 * 1024 * 2);
  unsigned short* Xql = (unsigned short*)alloc((size_t)32768 * 1024 * 2);
  float* hbuf  = (float*)alloc((size_t)64 * 1024 * 4);
  unsigned int* hbf01 = (unsigned int*)alloc((size_t)2 * 64 * 512 * 4);  // packed
  unsigned int* hrbf  = (unsigned int*)alloc((size_t)64 * 512 * 4);      // packed
  float* zbuf  = (float*)alloc((size_t)64 * 1024 * 4);
  unsigned int* bar = (unsigned int*)alloc((size_t)32768 * 4);  // 64 flags x 64B

  if (off > ws_size) {  // workspace too small: emit recognizable sentinel
    fill_sentinel<<<2048, 256, 0, stream>>>(out, out_size);
    return;
  }

  init_state<<<256, 256, 0, stream>>>(hbuf, hbf01, bar);

  dim3 tg(32, 32);
  transpose_w<<<tg, 256, 0, stream>>>(Wr, WrzT);                        // Wr_h^T
  transpose_w<<<tg, 256, 0, stream>>>(Wz, WrzT + 1024 * 1024);          // Wz_h^T
  transpose_w<<<tg, 256, 0, stream>>>(Wl, WlT);                         // Wl_h^T
  transpose_w<<<tg, 256, 0, stream>>>(Wo, WoT);                         // Wo^T
  transpose_w<<<tg, 256, 0, stream>>>(Wr + 1024 * 1024, WxT);           // Wr_x^T
  transpose_w<<<tg, 256, 0, stream>>>(Wz + 1024 * 1024, WxT + 1024 * 1024);
  transpose_w<<<tg, 256, 0, stream>>>(Wl + 1024 * 1024, WxT + 2 * 1024 * 1024);

  conv_x<<<16384, 256, 0, stream>>>(X, Xbf);

  // x-projections for all (b,t): bias folded, bf16 out in [t][b][h] layout
  gemm_x<<<dim3(24, 256), 256, 0, stream>>>(Xbf, WxT, Xqr, Xqz, Xql, br, bz, bl);

  // sequential recurrence + fused output projection
  seq_kernel<<<64, 1024, 0, stream>>>(WrzT, WlT, WoT,
                                      (const unsigned int*)Xqr,
                                      (const unsigned int*)Xqz,
                                      (const unsigned int*)Xql, bo,
                                      hbuf, hbf01, hrbf, zbuf, out, bar);
}

// Round 8
// 9059.032 us; speedup vs baseline: 2.1770x; 2.1770x over previous
//
#include <hip/hip_runtime.h>
#include <cstdint>

// GRU B=64 T=512 D=1024 H=1024, fp32 in/out, bf16 MFMA internally.
// [x-proj big GEMM -> bf16 Xq with bias] -> [sequential recurrence: 64 wgs x
// 1024 thr; LDS-resident weight slices; per-step ROTATING h buffers (fresh
// addresses -> plain cached reads are coherence-safe); sc1 write-through
// stores; fence-free flag barrier; z and fp32-h in registers; out-projection
// fused into barrier-wait windows].

typedef float f32x4 __attribute__((ext_vector_type(4)));
typedef short s16x8 __attribute__((ext_vector_type(8)));

#define AS_G const __attribute__((address_space(1))) unsigned int*
#define AS_L __attribute__((address_space(3))) unsigned int*

__device__ __forceinline__ unsigned short f2bf(float f) {
  union { float f; unsigned int u; } v; v.f = f;
  return (unsigned short)((v.u + 0x7FFFu + ((v.u >> 16) & 1u)) >> 16);
}
__device__ __forceinline__ float bf2f(unsigned short s) {
  union { unsigned int u; float f; } v; v.u = ((unsigned int)s) << 16;
  return v.f;
}

// sc1 write-through store (relaxed agent scope): lands at the coherent LLC,
// pipelined like a normal store, drained by vmcnt. Used ONLY for stores of
// cross-wg data and for barrier flags; all data LOADS are plain cached.
__device__ __forceinline__ void g_store32(unsigned int* p, unsigned int v) {
  __hip_atomic_store(p, v, __ATOMIC_RELAXED, __HIP_MEMORY_SCOPE_AGENT);
}
__device__ __forceinline__ unsigned int g_load32(const unsigned int* p) {
  return __hip_atomic_load((unsigned int*)p, __ATOMIC_RELAXED, __HIP_MEMORY_SCOPE_AGENT);
}

// ---------------- init / guard ----------------
__global__ void init_state(unsigned int* __restrict__ hb0,
                           unsigned int* __restrict__ bar) {
  int i = blockIdx.x * 256 + threadIdx.x;  // 32768 threads
  hb0[i] = 0u;                             // h_0 = 0 (slot 0, 64x512 dwords)
  if (i < 1024) bar[i] = 0u;
}

__global__ void fill_sentinel(float* o, int n) {
  for (int i = blockIdx.x * 256 + threadIdx.x; i < n; i += gridDim.x * 256)
    o[i] = 1.0e6f;  // recognizable "ws too small" marker
}

// ---------------- weight transpose: fp32 [1024][1024] -> bf16 [C][R]
__global__ void transpose_w(const float* __restrict__ src, short* __restrict__ dst) {
  __shared__ float t[32][33];
  const int bx = blockIdx.x, by = blockIdx.y;
  const int c = threadIdx.x & 31, r8 = threadIdx.x >> 5;
#pragma unroll
  for (int j = 0; j < 4; ++j) {
    int r = r8 + j * 8;
    t[r][c] = src[(by * 32 + r) * 1024 + bx * 32 + c];
  }
  __syncthreads();
#pragma unroll
  for (int j = 0; j < 4; ++j) {
    int d = r8 + j * 8;
    dst[(bx * 32 + d) * 1024 + by * 32 + c] = (short)f2bf(t[c][d]);
  }
}

// ---------------- X fp32 -> bf16 (layout-preserving), 8 elems/thread
__global__ void conv_x(const float* __restrict__ x, short* __restrict__ xb) {
  int i = blockIdx.x * 256 + threadIdx.x;  // 4,194,304 threads
  const float4* p = reinterpret_cast<const float4*>(x) + (size_t)i * 2;
  float4 a = p[0], b = p[1];
  s16x8 o;
  o[0] = (short)f2bf(a.x); o[1] = (short)f2bf(a.y);
  o[2] = (short)f2bf(a.z); o[3] = (short)f2bf(a.w);
  o[4] = (short)f2bf(b.x); o[5] = (short)f2bf(b.y);
  o[6] = (short)f2bf(b.z); o[7] = (short)f2bf(b.w);
  *reinterpret_cast<s16x8*>(xb + (size_t)i * 8) = o;
}

// ---------------- x-projection GEMM: [32768,1024]bf16 x [3072,1024]^T bf16
__global__ __launch_bounds__(256) void gemm_x(
    const short* __restrict__ A, const short* __restrict__ Bt,
    unsigned short* __restrict__ Xqr, unsigned short* __restrict__ Xqz,
    unsigned short* __restrict__ Xql,
    const float* __restrict__ br, const float* __restrict__ bz,
    const float* __restrict__ bl) {
  __shared__ short As[128 * 64];
  __shared__ short Bs[128 * 64];
  const int tid = threadIdx.x, wv = tid >> 6, l = tid & 63, lr = l & 15, lk = l >> 4;
  const int lin = blockIdx.y * 24 + blockIdx.x;       // XCD-chunked swizzle (T1)
  const int swz = (lin & 7) * 768 + (lin >> 3);
  const int bx = swz % 24, by = swz / 24;
  const int mh = wv >> 1, nh = wv & 1;

  f32x4 acc[4][4];
#pragma unroll
  for (int i = 0; i < 4; ++i)
#pragma unroll
    for (int j = 0; j < 4; ++j) acc[i][j] = (f32x4)0.f;

  const short* Ablk = A + (size_t)by * 128 * 1024;
  const short* Bblk = Bt + (size_t)bx * 128 * 1024;

  for (int kt = 0; kt < 16; ++kt) {
    __syncthreads();
    {
      const short* srcA = Ablk + kt * 64;
      const short* srcB = Bblk + kt * 64;
#pragma unroll
      for (int j = 0; j < 4; ++j) {
        int ubase = j * 256 + wv * 64;  // wave-uniform 16B-unit base
        int u = ubase + l;
        int r = u >> 3, cp = u & 7, c = cp ^ (r & 7);  // source-side pre-swizzle
        __builtin_amdgcn_global_load_lds((AS_G)(srcA + r * 1024 + c * 8),
                                         (AS_L)(As + ubase * 8), 16, 0, 0);
        __builtin_amdgcn_global_load_lds((AS_G)(srcB + r * 1024 + c * 8),
                                         (AS_L)(Bs + ubase * 8), 16, 0, 0);
      }
    }
    __syncthreads();
#pragma unroll
    for (int kc = 0; kc < 2; ++kc) {
      s16x8 af[4], bfr[4];
#pragma unroll
      for (int mt = 0; mt < 4; ++mt) {
        int r = mh * 64 + mt * 16 + lr;
        af[mt] = *(const s16x8*)(As + r * 64 + ((((kc << 2) + lk) ^ (r & 7)) << 3));
      }
#pragma unroll
      for (int nt = 0; nt < 4; ++nt) {
        int r = nh * 64 + nt * 16 + lr;
        bfr[nt] = *(const s16x8*)(Bs + r * 64 + ((((kc << 2) + lk) ^ (r & 7)) << 3));
      }
#pragma unroll
      for (int mt = 0; mt < 4; ++mt)
#pragma unroll
        for (int nt = 0; nt < 4; ++nt)
          acc[mt][nt] = __builtin_amdgcn_mfma_f32_16x16x32_bf16(af[mt], bfr[nt],
                                                                acc[mt][nt], 0, 0, 0);
    }
  }

  const int seg = bx >> 3;  // 0:r 1:z 2:l
  const float* __restrict__ bias = seg == 0 ? br : (seg == 1 ? bz : bl);
  unsigned short* __restrict__ dst = seg == 0 ? Xqr : (seg == 1 ? Xqz : Xql);
  const int cbase = (bx & 7) * 128 + nh * 64;
#pragma unroll
  for (int mt = 0; mt < 4; ++mt) {
#pragma unroll
    for (int j = 0; j < 4; ++j) {
      int R = by * 128 + mh * 64 + mt * 16 + lk * 4 + j;  // A row = b*512+t
      int tt = R & 511, b = R >> 9;
      size_t drow = ((size_t)((tt << 6) + b)) << 10;      // [t][b] order
#pragma unroll
      for (int nt = 0; nt < 4; ++nt) {
        int c = cbase + nt * 16 + lr;
        dst[drow + c] = f2bf(acc[mt][nt][j] + bias[c]);
      }
    }
  }
}

// ---------------- fence-free grid barrier ----------------
__device__ __forceinline__ void bar_arrive(unsigned int* bar, int g, unsigned int val) {
  __syncthreads();  // all threads' sc1 stores drained (vmcnt(0) before s_barrier)
  if (threadIdx.x == 0) g_store32(&bar[g << 4], val);
}
__device__ __forceinline__ void bar_wait(unsigned int* bar, unsigned int val,
                                         int wv, int l) {
  if (wv == 0) {
    while (g_load32(&bar[l << 4]) < val) __builtin_amdgcn_s_sleep(1);
  }
  __syncthreads();
}

// ---------------- fused out-projection ----------------
__device__ __forceinline__ void ldfrag_h(const short* __restrict__ hb,
                                         int lr, int lk, int k8, int mo, int oh,
                                         s16x8 hf[4]) {
#pragma unroll
  for (int kc = 0; kc < 4; ++kc) {
    const int k0 = (k8 << 7) + (kc << 5) + (lk << 3);
    hf[kc] = *(const s16x8*)(hb + ((oh * 32 + mo * 16 + lr) << 10) + k0);
  }
}
// relu(h @ Wo + bo) for one 32-row half. redf viewed [8][32][18].
__device__ __forceinline__ void outproj(const s16x8 wo[4], const s16x8 hf[4],
                                        const float* __restrict__ bo,
                                        float* __restrict__ out, float* redf,
                                        int g, int tid, int lr, int lk, int k8,
                                        int mo, int tOut, int oh) {
  f32x4 acc = (f32x4)0.f;
#pragma unroll
  for (int kc = 0; kc < 4; ++kc)
    acc = __builtin_amdgcn_mfma_f32_16x16x32_bf16(hf[kc], wo[kc], acc, 0, 0, 0);
  __syncthreads();  // prior red readers done before overwrite
#pragma unroll
  for (int j = 0; j < 4; ++j)
    redf[((k8 << 5) + mo * 16 + lk * 4 + j) * 18 + lr] = acc[j];
  __syncthreads();
  if (tid < 512) {
    const int r = tid >> 4, c = tid & 15;
    float s = 0.f;
#pragma unroll
    for (int q = 0; q < 8; ++q) s += redf[((q << 5) + r) * 18 + c];
    const int gcol = (g << 4) + c;
    const int brow = oh * 32 + r;
    out[(((size_t)brow << 9) + (size_t)tOut) * 1024 + gcol] = fmaxf(s + bo[gcol], 0.f);
  }
}

// ---------------- sequential recurrence: 64 wgs x 1024 threads (16 waves)
// wg g owns output columns [16g, 16g+16) end-to-end: computes r AND z there
// (z stays in a register), then hh and the h-update (fp32 h in a register).
// Cross-wg data: bf16 h and bf16 h*r, in per-step rotating slots (128 KiB).
__global__ __launch_bounds__(1024) void seq_kernel(
    const short* __restrict__ WrzT, const short* __restrict__ WlT,
    const short* __restrict__ WoT,
    const unsigned short* __restrict__ Xqr, const unsigned short* __restrict__ Xqz,
    const unsigned short* __restrict__ Xql, const float* __restrict__ bo,
    unsigned int* __restrict__ HB,   // 513 slots x 32768 dwords (bf16 h)
    unsigned int* __restrict__ HR,   // 512 slots x 32768 dwords (bf16 h*r)
    float* __restrict__ out, unsigned int* __restrict__ bar) {
  __shared__ short WrzS[32 * 1024];   // 64 KiB: rows 0-15 Wr cols, 16-31 Wz cols
  __shared__ short WlS[16 * 1024];    // 32 KiB
  __shared__ float red[4][64][37];    // 37 KiB cross-wave K-reduction

  const int g = blockIdx.x, tid = threadIdx.x;
  const int wv = tid >> 6, l = tid & 63, lr = l & 15, lk = l >> 4;
  float* redf = &red[0][0][0];

  // ---- stage weight slices into LDS (XOR-swizzled 16B units) ----
  for (int u = tid; u < 32 * 128; u += 1024) {
    int row = u >> 7, ku = u & 127;
    int srcr = (row < 16) ? (g * 16 + row) : (1024 + g * 16 + row - 16);
    s16x8 v = *(const s16x8*)(WrzT + ((size_t)srcr << 10) + (ku << 3));
    *(s16x8*)(WrzS + (row << 10) + ((ku ^ (row & 7)) << 3)) = v;
  }
  for (int u = tid; u < 16 * 128; u += 1024) {
    int row = u >> 7, ku = u & 127;
    s16x8 v = *(const s16x8*)(WlT + (((size_t)(g * 16 + row)) << 10) + (ku << 3));
    *(s16x8*)(WlS + (row << 10) + ((ku ^ (row & 7)) << 3)) = v;
  }

  // wave roles
  const int kqA = wv & 3, ntA = (wv >> 2) & 1, mhA = wv >> 3;  // phase A
  const int browA = ntA * 16 + lr;
  const int kqB = wv & 3, mqB = wv >> 2;                       // phase B
  const int k8 = wv & 7, mo = wv >> 3;                         // out-proj
  const int erow = tid >> 4, ecol = tid & 15;                  // epilogues

  // per-thread persistent state (column 16g+ecol, batch row erow)
  float hreg = 0.f, zreg = 0.f;

  // hoist Wo fragments (loop-invariant)
  s16x8 wo[4];
#pragma unroll
  for (int kc = 0; kc < 4; ++kc) {
    const int k0 = (k8 << 7) + (kc << 5) + (lk << 3);
    wo[kc] = *(const s16x8*)(WoT + (((size_t)(g << 4) + lr) << 10) + k0);
  }
  __syncthreads();

  for (int t = 0; t < 512; ++t) {
    const short* hbT = (const short*)(HB + (size_t)t * 32768);       // h_t
    unsigned int* hbN = HB + (size_t)(t + 1) * 32768;                // h_{t+1}
    const short* hrT = (const short*)(HR + (size_t)t * 32768);       // (h.r)_t
    unsigned int* hrW = HR + (size_t)t * 32768;
    // ================= Phase A: r,z for cols [16g,16g+16) =================
    {
      f32x4 acc0 = (f32x4)0.f, acc1 = (f32x4)0.f;
#pragma unroll 2
      for (int kc = 0; kc < 8; ++kc) {
        const int k0 = (kqA << 8) + (kc << 5) + (lk << 3);
        const int ku = k0 >> 3;
        s16x8 bb = *(const s16x8*)(WrzS + (browA << 10) + ((ku ^ (browA & 7)) << 3));
        s16x8 a0 = *(const s16x8*)(hbT + ((mhA * 32 + lr) << 10) + k0);
        s16x8 a1 = *(const s16x8*)(hbT + ((mhA * 32 + 16 + lr) << 10) + k0);
        acc0 = __builtin_amdgcn_mfma_f32_16x16x32_bf16(a0, bb, acc0, 0, 0, 0);
        acc1 = __builtin_amdgcn_mfma_f32_16x16x32_bf16(a1, bb, acc1, 0, 0, 0);
      }
#pragma unroll
      for (int j = 0; j < 4; ++j) {
        red[kqA][mhA * 32 + lk * 4 + j][ntA * 16 + lr] = acc0[j];
        red[kqA][mhA * 32 + 16 + lk * 4 + j][ntA * 16 + lr] = acc1[j];
      }
      const size_t xi = ((((size_t)t << 6) + erow) << 10) + (g << 4) + ecol;
      float xr = bf2f(Xqr[xi]);
      float xz = bf2f(Xqz[xi]);
      __syncthreads();
      float rs = red[0][erow][ecol] + red[1][erow][ecol] + red[2][erow][ecol] +
                 red[3][erow][ecol] + xr;
      float zs = red[0][erow][ecol + 16] + red[1][erow][ecol + 16] +
                 red[2][erow][ecol + 16] + red[3][erow][ecol + 16] + xz;
      float r = 1.f / (1.f + __expf(-rs));
      zreg = 1.f / (1.f + __expf(-zs));
      unsigned int hv = (unsigned int)f2bf(hreg * r);
      unsigned int up = (unsigned int)__shfl_down((int)hv, 1);
      if (!(ecol & 1))
        g_store32(hrW + (erow << 9) + (g << 3) + (ecol >> 1), hv | (up << 16));
    }
    s16x8 hf0[4];
    if (t > 0) ldfrag_h(hbT, lr, lk, k8, mo, 0, hf0);
    bar_arrive(bar, g, 2 * t + 1);
    if (t > 0) outproj(wo, hf0, bo, out, redf, g, tid, lr, lk, k8, mo, t - 1, 0);
    bar_wait(bar, 2 * t + 1, wv, l);
    // ================= Phase B: hh + update for cols [16g,16g+16) ==========
    {
      f32x4 acc = (f32x4)0.f;
#pragma unroll 2
      for (int kc = 0; kc < 8; ++kc) {
        const int k0 = (kqB << 8) + (kc << 5) + (lk << 3);
        const int ku = k0 >> 3;
        s16x8 bb = *(const s16x8*)(WlS + (lr << 10) + ((ku ^ (lr & 7)) << 3));
        s16x8 af = *(const s16x8*)(hrT + ((mqB * 16 + lr) << 10) + k0);
        acc = __builtin_amdgcn_mfma_f32_16x16x32_bf16(af, bb, acc, 0, 0, 0);
      }
#pragma unroll
      for (int j = 0; j < 4; ++j) red[kqB][mqB * 16 + lk * 4 + j][lr] = acc[j];
      float xl = bf2f(Xql[((((size_t)t << 6) + erow) << 10) + (g << 4) + ecol]);
      __syncthreads();
      float pre = red[0][erow][ecol] + red[1][erow][ecol] + red[2][erow][ecol] +
                  red[3][erow][ecol] + xl;
      float a = fabsf(pre);
      float e = __expf(-2.f * a);
      float m = (1.f - e) / (1.f + e);     // tanh(|pre|), overflow-safe
      float hh = pre < 0.f ? -m : m;
      hreg = hreg + zreg * (hh - hreg);    // (1-z)h + z*hh
      unsigned int hv = (unsigned int)f2bf(hreg);
      unsigned int up = (unsigned int)__shfl_down((int)hv, 1);
      if (!(ecol & 1))
        g_store32(hbN + (erow << 9) + (g << 3) + (ecol >> 1), hv | (up << 16));
    }
    s16x8 hf1[4];
    if (t > 0) ldfrag_h(hbT, lr, lk, k8, mo, 1, hf1);
    bar_arrive(bar, g, 2 * t + 2);
    if (t > 0) outproj(wo, hf1, bo, out, redf, g, tid, lr, lk, k8, mo, t - 1, 1);
    bar_wait(bar, 2 * t + 2, wv, l);
  }
  // final output rows (t = 511): h_512 in slot 512
  {
    const short* hlast = (const short*)(HB + (size_t)512 * 32768);
    s16x8 hf[4];
    ldfrag_h(hlast, lr, lk, k8, mo, 0, hf);
    outproj(wo, hf, bo, out, redf, g, tid, lr, lk, k8, mo, 511, 0);
    ldfrag_h(hlast, lr, lk, k8, mo, 1, hf);
    outproj(wo, hf, bo, out, redf, g, tid, lr, lk, k8, mo, 511, 1);
  }
}

// ---------------- host ----------------
extern "C" void kernel_launch(void* const* d_in, const int* in_sizes, int n_in,
                              void* d_out, int out_size, void* d_ws, size_t ws_size,
                              hipStream_t stream) {
  (void)in_sizes; (void)n_in;
  const float* X  = (const float*)d_in[0];
  const float* Wr = (const float*)d_in[1];
  const float* br = (const float*)d_in[2];
  const float* Wz = (const float*)d_in[3];
  const float* bz = (const float*)d_in[4];
  const float* Wl = (const float*)d_in[5];
  const float* bl = (const float*)d_in[6];
  const float* Wo = (const float*)d_in[7];
  const float* bo = (const float*)d_in[8];
  float* out = (float*)d_out;

  char* ws = (char*)d_ws;
  size_t off = 0;
  auto alloc = [&](size_t bytes) -> char* {
    char* p = ws + off;
    off += (bytes + 255) & ~(size_t)255;
    return p;
  };
  short* WrzT = (short*)alloc((size_t)2048 * 1024 * 2);   // [Wr_h^T ; Wz_h^T]
  short* WlT  = (short*)alloc((size_t)1024 * 1024 * 2);
  short* WoT  = (short*)alloc((size_t)1024 * 1024 * 2);
  short* WxT  = (short*)alloc((size_t)3072 * 1024 * 2);   // [Wr_x^T;Wz_x^T;Wl_x^T]
  short* Xbf  = (short*)alloc((size_t)32768 * 1024 * 2);
  unsigned short* Xqr = (unsigned short*)alloc((size_t)32768 * 1024 * 2);
  unsigned short* Xqz = (unsigned short*)alloc((size_t)32768 * 1024 * 2);
  unsigned short* Xql = (unsigned short*)alloc((size_t)32768 * 1024 * 2);
  unsigned int* HB  = (unsigned int*)alloc((size_t)513 * 32768 * 4);  // h rot
  unsigned int* HR  = (unsigned int*)alloc((size_t)512 * 32768 * 4);  // h.r rot
  unsigned int* bar = (unsigned int*)alloc((size_t)1024 * 4);         // 64 x 64B

  if (off > ws_size) {  // workspace too small: emit recognizable sentinel
    fill_sentinel<<<2048, 256, 0, stream>>>(out, out_size);
    return;
  }

  init_state<<<128, 256, 0, stream>>>(HB, bar);

  dim3 tg(32, 32);
  transpose_w<<<tg, 256, 0, stream>>>(Wr, WrzT);                        // Wr_h^T
  transpose_w<<<tg, 256, 0, stream>>>(Wz, WrzT + 1024 * 1024);          // Wz_h^T
  transpose_w<<<tg, 256, 0, stream>>>(Wl, WlT);                         // Wl_h^T
  transpose_w<<<tg, 256, 0, stream>>>(Wo, WoT);                         // Wo^T
  transpose_w<<<tg, 256, 0, stream>>>(Wr + 1024 * 1024, WxT);           // Wr_x^T
  transpose_w<<<tg, 256, 0, stream>>>(Wz + 1024 * 1024, WxT + 1024 * 1024);
  transpose_w<<<tg, 256, 0, stream>>>(Wl + 1024 * 1024, WxT + 2 * 1024 * 1024);

  conv_x<<<16384, 256, 0, stream>>>(X, Xbf);

  // x-projections for all (b,t): bias folded, bf16 out in [t][b][h] layout
  gemm_x<<<dim3(24, 256), 256, 0, stream>>>(Xbf, WxT, Xqr, Xqz, Xql, br, bz, bl);

  // sequential recurrence + fused output projection
  seq_kernel<<<64, 1024, 0, stream>>>(WrzT, WlT, WoT, Xqr, Xqz, Xql, bo,
                                      HB, HR, out, bar);
}

// Round 11
// 5800.898 us; speedup vs baseline: 3.3997x; 1.5617x over previous
//
#include <hip/hip_runtime.h>
#include <cstdint>

// GRU B=64 T=512 D=1024 H=1024, fp32 in/out, bf16 MFMA internally.
// [x-proj big GEMM -> bf16 Xq with bias] -> [sequential recurrence: 64 wgs x
// 1024 thr; LDS weight slices; rotating write-once h/hr slots (plain cached
// reads coherence-safe); sc1 write-through stores; fence-free flag barrier;
// unified (kq,mq) wave partition: phase-A h-fragments kept in REGISTERS and
// reused as the out-projection A-operand (zero extra h traffic); Wo hoisted].

typedef float f32x4 __attribute__((ext_vector_type(4)));
typedef short s16x8 __attribute__((ext_vector_type(8)));

#define AS_G const __attribute__((address_space(1))) unsigned int*
#define AS_L __attribute__((address_space(3))) unsigned int*

__device__ __forceinline__ unsigned short f2bf(float f) {
  union { float f; unsigned int u; } v; v.f = f;
  return (unsigned short)((v.u + 0x7FFFu + ((v.u >> 16) & 1u)) >> 16);
}
__device__ __forceinline__ float bf2f(unsigned short s) {
  union { unsigned int u; float f; } v; v.u = ((unsigned int)s) << 16;
  return v.f;
}

// sc1 write-through store (relaxed agent scope): lands at the coherent LLC.
// Used ONLY for cross-wg stores + barrier flags; all data LOADS plain cached.
__device__ __forceinline__ void g_store32(unsigned int* p, unsigned int v) {
  __hip_atomic_store(p, v, __ATOMIC_RELAXED, __HIP_MEMORY_SCOPE_AGENT);
}
__device__ __forceinline__ unsigned int g_load32(const unsigned int* p) {
  return __hip_atomic_load((unsigned int*)p, __ATOMIC_RELAXED, __HIP_MEMORY_SCOPE_AGENT);
}

// ---------------- init / guard ----------------
__global__ void init_state(unsigned int* __restrict__ hb0,
                           unsigned int* __restrict__ bar) {
  int i = blockIdx.x * 256 + threadIdx.x;  // 32768 threads
  hb0[i] = 0u;                             // h_0 = 0 (slot 0, 64x512 dwords)
  if (i < 1024) bar[i] = 0u;
}

__global__ void fill_sentinel(float* o, int n) {
  for (int i = blockIdx.x * 256 + threadIdx.x; i < n; i += gridDim.x * 256)
    o[i] = 1.0e6f;  // recognizable "ws too small" marker
}

// ---------------- weight transpose: fp32 [1024][1024] -> bf16 [C][R]
__global__ void transpose_w(const float* __restrict__ src, short* __restrict__ dst) {
  __shared__ float t[32][33];
  const int bx = blockIdx.x, by = blockIdx.y;
  const int c = threadIdx.x & 31, r8 = threadIdx.x >> 5;
#pragma unroll
  for (int j = 0; j < 4; ++j) {
    int r = r8 + j * 8;
    t[r][c] = src[(by * 32 + r) * 1024 + bx * 32 + c];
  }
  __syncthreads();
#pragma unroll
  for (int j = 0; j < 4; ++j) {
    int d = r8 + j * 8;
    dst[(bx * 32 + d) * 1024 + by * 32 + c] = (short)f2bf(t[c][d]);
  }
}

// ---------------- X fp32 -> bf16 (layout-preserving), 8 elems/thread
__global__ void conv_x(const float* __restrict__ x, short* __restrict__ xb) {
  int i = blockIdx.x * 256 + threadIdx.x;  // 4,194,304 threads
  const float4* p = reinterpret_cast<const float4*>(x) + (size_t)i * 2;
  float4 a = p[0], b = p[1];
  s16x8 o;
  o[0] = (short)f2bf(a.x); o[1] = (short)f2bf(a.y);
  o[2] = (short)f2bf(a.z); o[3] = (short)f2bf(a.w);
  o[4] = (short)f2bf(b.x); o[5] = (short)f2bf(b.y);
  o[6] = (short)f2bf(b.z); o[7] = (short)f2bf(b.w);
  *reinterpret_cast<s16x8*>(xb + (size_t)i * 8) = o;
}

// ---------------- x-projection GEMM: [32768,1024]bf16 x [3072,1024]^T bf16
__global__ __launch_bounds__(256) void gemm_x(
    const short* __restrict__ A, const short* __restrict__ Bt,
    unsigned short* __restrict__ Xqr, unsigned short* __restrict__ Xqz,
    unsigned short* __restrict__ Xql,
    const float* __restrict__ br, const float* __restrict__ bz,
    const float* __restrict__ bl) {
  __shared__ short As[128 * 64];
  __shared__ short Bs[128 * 64];
  const int tid = threadIdx.x, wv = tid >> 6, l = tid & 63, lr = l & 15, lk = l >> 4;
  const int lin = blockIdx.y * 24 + blockIdx.x;       // XCD-chunked swizzle (T1)
  const int swz = (lin & 7) * 768 + (lin >> 3);
  const int bx = swz % 24, by = swz / 24;
  const int mh = wv >> 1, nh = wv & 1;

  f32x4 acc[4][4];
#pragma unroll
  for (int i = 0; i < 4; ++i)
#pragma unroll
    for (int j = 0; j < 4; ++j) acc[i][j] = (f32x4)0.f;

  const short* Ablk = A + (size_t)by * 128 * 1024;
  const short* Bblk = Bt + (size_t)bx * 128 * 1024;

  for (int kt = 0; kt < 16; ++kt) {
    __syncthreads();
    {
      const short* srcA = Ablk + kt * 64;
      const short* srcB = Bblk + kt * 64;
#pragma unroll
      for (int j = 0; j < 4; ++j) {
        int ubase = j * 256 + wv * 64;  // wave-uniform 16B-unit base
        int u = ubase + l;
        int r = u >> 3, cp = u & 7, c = cp ^ (r & 7);  // source-side pre-swizzle
        __builtin_amdgcn_global_load_lds((AS_G)(srcA + r * 1024 + c * 8),
                                         (AS_L)(As + ubase * 8), 16, 0, 0);
        __builtin_amdgcn_global_load_lds((AS_G)(srcB + r * 1024 + c * 8),
                                         (AS_L)(Bs + ubase * 8), 16, 0, 0);
      }
    }
    __syncthreads();
#pragma unroll
    for (int kc = 0; kc < 2; ++kc) {
      s16x8 af[4], bfr[4];
#pragma unroll
      for (int mt = 0; mt < 4; ++mt) {
        int r = mh * 64 + mt * 16 + lr;
        af[mt] = *(const s16x8*)(As + r * 64 + ((((kc << 2) + lk) ^ (r & 7)) << 3));
      }
#pragma unroll
      for (int nt = 0; nt < 4; ++nt) {
        int r = nh * 64 + nt * 16 + lr;
        bfr[nt] = *(const s16x8*)(Bs + r * 64 + ((((kc << 2) + lk) ^ (r & 7)) << 3));
      }
#pragma unroll
      for (int mt = 0; mt < 4; ++mt)
#pragma unroll
        for (int nt = 0; nt < 4; ++nt)
          acc[mt][nt] = __builtin_amdgcn_mfma_f32_16x16x32_bf16(af[mt], bfr[nt],
                                                                acc[mt][nt], 0, 0, 0);
    }
  }

  const int seg = bx >> 3;  // 0:r 1:z 2:l
  const float* __restrict__ bias = seg == 0 ? br : (seg == 1 ? bz : bl);
  unsigned short* __restrict__ dst = seg == 0 ? Xqr : (seg == 1 ? Xqz : Xql);
  const int cbase = (bx & 7) * 128 + nh * 64;
#pragma unroll
  for (int mt = 0; mt < 4; ++mt) {
#pragma unroll
    for (int j = 0; j < 4; ++j) {
      int R = by * 128 + mh * 64 + mt * 16 + lk * 4 + j;  // A row = b*512+t
      int tt = R & 511, b = R >> 9;
      size_t drow = ((size_t)((tt << 6) + b)) << 10;      // [t][b] order
#pragma unroll
      for (int nt = 0; nt < 4; ++nt) {
        int c = cbase + nt * 16 + lr;
        dst[drow + c] = f2bf(acc[mt][nt][j] + bias[c]);
      }
    }
  }
}

// ---------------- fence-free grid barrier ----------------
__device__ __forceinline__ void bar_arrive(unsigned int* bar, int g, unsigned int val) {
  __syncthreads();  // all threads' sc1 stores drained (vmcnt(0) before s_barrier)
  if (threadIdx.x == 0) g_store32(&bar[g << 4], val);
}
__device__ __forceinline__ void bar_wait(unsigned int* bar, unsigned int val,
                                         int wv, int l) {
  if (wv == 0) {
    while (g_load32(&bar[l << 4]) < val) __builtin_amdgcn_s_sleep(1);
  }
  __syncthreads();
}

// ---------------- sequential recurrence: 64 wgs x 1024 threads (16 waves)
// Unified wave partition: kq = wv&3 (K-quarter), mq = wv>>2 (16-row M-group).
// Phase A: r,z for cols [16g,16g+16); h-fragments af[8] KEPT in registers.
// Window 1: out_{t-1} = relu(h_t @ Wo + bo) reusing af (zero h re-reads).
// Phase B: hh + h-update; h fp32 and z live in registers.
// Window 2: prefetch Xq(t+1). Cross-wg: bf16 h / h*r in rotating slots.
__global__ __launch_bounds__(1024, 4) void seq_kernel(
    const short* __restrict__ WrzT, const short* __restrict__ WlT,
    const short* __restrict__ WoT,
    const unsigned short* __restrict__ Xqr, const unsigned short* __restrict__ Xqz,
    const unsigned short* __restrict__ Xql, const float* __restrict__ bo,
    unsigned int* __restrict__ HB,   // 513 slots x 32768 dwords (bf16 h)
    unsigned int* __restrict__ HR,   // 512 slots x 32768 dwords (bf16 h*r)
    float* __restrict__ out, unsigned int* __restrict__ bar) {
  __shared__ short WrzS[32 * 1024];   // 64 KiB: rows 0-15 Wr cols, 16-31 Wz cols
  __shared__ short WlS[16 * 1024];    // 32 KiB
  __shared__ float red[4][64][40];    // 40 KiB; stride 40 -> <=2-way read banks

  const int g = blockIdx.x, tid = threadIdx.x;
  const int wv = tid >> 6, l = tid & 63, lr = l & 15, lk = l >> 4;
  const int kq = wv & 3, mq = wv >> 2;          // unified roles
  const int erow = tid >> 4, ecol = tid & 15;   // epilogues
  const int gc = (g << 4) + ecol;

  // ---- stage weight slices into LDS (XOR-swizzled 16B units) ----
  for (int u = tid; u < 32 * 128; u += 1024) {
    int row = u >> 7, ku = u & 127;
    int srcr = (row < 16) ? (g * 16 + row) : (1024 + g * 16 + row - 16);
    s16x8 v = *(const s16x8*)(WrzT + ((size_t)srcr << 10) + (ku << 3));
    *(s16x8*)(WrzS + (row << 10) + ((ku ^ (row & 7)) << 3)) = v;
  }
  for (int u = tid; u < 16 * 128; u += 1024) {
    int row = u >> 7, ku = u & 127;
    s16x8 v = *(const s16x8*)(WlT + (((size_t)(g * 16 + row)) << 10) + (ku << 3));
    *(s16x8*)(WlS + (row << 10) + ((ku ^ (row & 7)) << 3)) = v;
  }

  // hoist Wo fragments for this wave's (kq) K-quarter (loop-invariant)
  s16x8 woq[8];
#pragma unroll
  for (int kc = 0; kc < 8; ++kc) {
    const int k0 = (kq << 8) + (kc << 5) + (lk << 3);
    woq[kc] = *(const s16x8*)(WoT + (((size_t)(g << 4) + lr) << 10) + k0);
  }

  // per-thread persistent state (column gc, batch row erow)
  float hreg = 0.f, zreg = 0.f;
  // preload Xq for t=0
  float xr, xz, xl;
  {
    const size_t xi = ((size_t)erow << 10) + gc;
    xr = bf2f(Xqr[xi]); xz = bf2f(Xqz[xi]); xl = bf2f(Xql[xi]);
  }
  __syncthreads();

  for (int t = 0; t < 512; ++t) {
    const short* hbT = (const short*)(HB + (size_t)t * 32768);       // h_t
    unsigned int* hbN = HB + (size_t)(t + 1) * 32768;                // h_{t+1}
    const short* hrT = (const short*)(HR + (size_t)t * 32768);       // (h.r)_t
    unsigned int* hrW = HR + (size_t)t * 32768;

    // ====== Phase A: r,z; af[8] (h_t fragments) stay live for outproj ======
    s16x8 af[8];
    {
      f32x4 acc0 = (f32x4)0.f, acc1 = (f32x4)0.f;
#pragma unroll
      for (int kc = 0; kc < 8; ++kc) {
        const int k0 = (kq << 8) + (kc << 5) + (lk << 3);
        const int ku = k0 >> 3;
        af[kc] = *(const s16x8*)(hbT + ((mq * 16 + lr) << 10) + k0);
        s16x8 b0 = *(const s16x8*)(WrzS + (lr << 10) + ((ku ^ (lr & 7)) << 3));
        s16x8 b1 = *(const s16x8*)(WrzS + ((16 + lr) << 10) + ((ku ^ (lr & 7)) << 3));
        acc0 = __builtin_amdgcn_mfma_f32_16x16x32_bf16(af[kc], b0, acc0, 0, 0, 0);
        acc1 = __builtin_amdgcn_mfma_f32_16x16x32_bf16(af[kc], b1, acc1, 0, 0, 0);
      }
#pragma unroll
      for (int j = 0; j < 4; ++j) {
        red[kq][mq * 16 + lk * 4 + j][lr] = acc0[j];        // r partials
        red[kq][mq * 16 + lk * 4 + j][16 + lr] = acc1[j];   // z partials
      }
      __syncthreads();
      float rs = red[0][erow][ecol] + red[1][erow][ecol] + red[2][erow][ecol] +
                 red[3][erow][ecol] + xr;
      float zs = red[0][erow][ecol + 16] + red[1][erow][ecol + 16] +
                 red[2][erow][ecol + 16] + red[3][erow][ecol + 16] + xz;
      float r = 1.f / (1.f + __expf(-rs));
      zreg = 1.f / (1.f + __expf(-zs));
      unsigned int hv = (unsigned int)f2bf(hreg * r);
      unsigned int up = (unsigned int)__shfl_down((int)hv, 1);
      if (!(ecol & 1))
        g_store32(hrW + (erow << 9) + (gc >> 1), hv | (up << 16));
    }
    bar_arrive(bar, g, 2 * t + 1);
    // ====== Window 1: out_{t-1} = relu(h_t @ Wo + bo), af reused ======
    if (t > 0) {
      f32x4 ao = (f32x4)0.f;
#pragma unroll
      for (int kc = 0; kc < 8; ++kc)
        ao = __builtin_amdgcn_mfma_f32_16x16x32_bf16(af[kc], woq[kc], ao, 0, 0, 0);
#pragma unroll
      for (int j = 0; j < 4; ++j) red[kq][mq * 16 + lk * 4 + j][lr] = ao[j];
      __syncthreads();
      float s = red[0][erow][ecol] + red[1][erow][ecol] + red[2][erow][ecol] +
                red[3][erow][ecol] + bo[gc];
      out[(((size_t)((erow << 9) + (t - 1))) << 10) + gc] = fmaxf(s, 0.f);
    }
    bar_wait(bar, 2 * t + 1, wv, l);
    // ====== Phase B: hh + h-update for cols [16g,16g+16) ======
    {
      f32x4 accB = (f32x4)0.f;
#pragma unroll
      for (int kc = 0; kc < 8; ++kc) {
        const int k0 = (kq << 8) + (kc << 5) + (lk << 3);
        const int ku = k0 >> 3;
        s16x8 bb = *(const s16x8*)(WlS + (lr << 10) + ((ku ^ (lr & 7)) << 3));
        s16x8 ab = *(const s16x8*)(hrT + ((mq * 16 + lr) << 10) + k0);
        accB = __builtin_amdgcn_mfma_f32_16x16x32_bf16(ab, bb, accB, 0, 0, 0);
      }
#pragma unroll
      for (int j = 0; j < 4; ++j) red[kq][mq * 16 + lk * 4 + j][lr] = accB[j];
      __syncthreads();
      float pre = red[0][erow][ecol] + red[1][erow][ecol] + red[2][erow][ecol] +
                  red[3][erow][ecol] + xl;
      float a = fabsf(pre);
      float e = __expf(-2.f * a);
      float m = (1.f - e) / (1.f + e);     // tanh(|pre|), overflow-safe
      float hh = pre < 0.f ? -m : m;
      hreg = hreg + zreg * (hh - hreg);    // (1-z)h + z*hh
      unsigned int hv = (unsigned int)f2bf(hreg);
      unsigned int up = (unsigned int)__shfl_down((int)hv, 1);
      if (!(ecol & 1))
        g_store32(hbN + (erow << 9) + (gc >> 1), hv | (up << 16));
    }
    bar_arrive(bar, g, 2 * t + 2);
    // ====== Window 2: prefetch Xq for t+1 (hides cold-HBM latency) ======
    {
      const int tn = (t + 1 < 512) ? t + 1 : 511;
      const size_t xi = ((((size_t)tn << 6) + erow) << 10) + gc;
      xr = bf2f(Xqr[xi]); xz = bf2f(Xqz[xi]); xl = bf2f(Xql[xi]);
    }
    bar_wait(bar, 2 * t + 2, wv, l);
  }
  // ====== Tail: out_{511} = relu(h_512 @ Wo + bo) ======
  {
    const short* hl = (const short*)(HB + (size_t)512 * 32768);
    f32x4 ao = (f32x4)0.f;
#pragma unroll
    for (int kc = 0; kc < 8; ++kc) {
      const int k0 = (kq << 8) + (kc << 5) + (lk << 3);
      s16x8 a = *(const s16x8*)(hl + ((mq * 16 + lr) << 10) + k0);
      ao = __builtin_amdgcn_mfma_f32_16x16x32_bf16(a, woq[kc], ao, 0, 0, 0);
    }
#pragma unroll
    for (int j = 0; j < 4; ++j) red[kq][mq * 16 + lk * 4 + j][lr] = ao[j];
    __syncthreads();
    float s = red[0][erow][ecol] + red[1][erow][ecol] + red[2][erow][ecol] +
              red[3][erow][ecol] + bo[gc];
    out[(((size_t)((erow << 9) + 511)) << 10) + gc] = fmaxf(s, 0.f);
  }
}

// ---------------- host ----------------
extern "C" void kernel_launch(void* const* d_in, const int* in_sizes, int n_in,
                              void* d_out, int out_size, void* d_ws, size_t ws_size,
                              hipStream_t stream) {
  (void)in_sizes; (void)n_in;
  const float* X  = (const float*)d_in[0];
  const float* Wr = (const float*)d_in[1];
  const float* br = (const float*)d_in[2];
  const float* Wz = (const float*)d_in[3];
  const float* bz = (const float*)d_in[4];
  const float* Wl = (const float*)d_in[5];
  const float* bl = (const float*)d_in[6];
  const float* Wo = (const float*)d_in[7];
  const float* bo = (const float*)d_in[8];
  float* out = (float*)d_out;

  char* ws = (char*)d_ws;
  size_t off = 0;
  auto alloc = [&](size_t bytes) -> char* {
    char* p = ws + off;
    off += (bytes + 255) & ~(size_t)255;
    return p;
  };
  short* WrzT = (short*)alloc((size_t)2048 * 1024 * 2);   // [Wr_h^T ; Wz_h^T]
  short* WlT  = (short*)alloc((size_t)1024 * 1024 * 2);
  short* WoT  = (short*)alloc((size_t)1024 * 1024 * 2);
  short* WxT  = (short*)alloc((size_t)3072 * 1024 * 2);   // [Wr_x^T;Wz_x^T;Wl_x^T]
  short* Xbf  = (short*)alloc((size_t)32768 * 1024 * 2);
  unsigned short* Xqr = (unsigned short*)alloc((size_t)32768 * 1024 * 2);
  unsigned short* Xqz = (unsigned short*)alloc((size_t)32768 * 1024 * 2);
  unsigned short* Xql = (unsigned short*)alloc((size_t)32768 * 1024 * 2);
  unsigned int* HB  = (unsigned int*)alloc((size_t)513 * 32768 * 4);  // h rot
  unsigned int* HR  = (unsigned int*)alloc((size_t)512 * 32768 * 4);  // h.r rot
  unsigned int* bar = (unsigned int*)alloc((size_t)1024 * 4);         // 64 x 64B

  if (off > ws_size) {  // workspace too small: emit recognizable sentinel
    fill_sentinel<<<2048, 256, 0, stream>>>(out, out_size);
    return;
  }

  init_state<<<128, 256, 0, stream>>>(HB, bar);

  dim3 tg(32, 32);
  transpose_w<<<tg, 256, 0, stream>>>(Wr, WrzT);                        // Wr_h^T
  transpose_w<<<tg, 256, 0, stream>>>(Wz, WrzT + 1024 * 1024);          // Wz_h^T
  transpose_w<<<tg, 256, 0, stream>>>(Wl, WlT);                         // Wl_h^T
  transpose_w<<<tg, 256, 0, stream>>>(Wo, WoT);                         // Wo^T
  transpose_w<<<tg, 256, 0, stream>>>(Wr + 1024 * 1024, WxT);           // Wr_x^T
  transpose_w<<<tg, 256, 0, stream>>>(Wz + 1024 * 1024, WxT + 1024 * 1024);
  transpose_w<<<tg, 256, 0, stream>>>(Wl + 1024 * 1024, WxT + 2 * 1024 * 1024);

  conv_x<<<16384, 256, 0, stream>>>(X, Xbf);

  // x-projections for all (b,t): bias folded, bf16 out in [t][b][h] layout
  gemm_x<<<dim3(24, 256), 256, 0, stream>>>(Xbf, WxT, Xqr, Xqz, Xql, br, bz, bl);

  // sequential recurrence + fused output projection
  seq_kernel<<<64, 1024, 0, stream>>>(WrzT, WlT, WoT, Xqr, Xqz, Xql, bo,
                                      HB, HR, out, bar);
}